// Round 12
// baseline (833.838 us; speedup 1.0000x reference)
//
#include <hip/hip_runtime.h>
#include <hip/hip_bf16.h>
#include <cmath>

typedef __bf16 bf16;
typedef __attribute__((ext_vector_type(8))) __bf16 bf16x8;
typedef __attribute__((ext_vector_type(4))) __bf16 bf16x4;
typedef __attribute__((ext_vector_type(4))) float f32x4;
typedef unsigned long long ull;

#define TEMPC 65.0f
#define EPSC 1e-6f

#define GLD_LDS16(gptr, lptr)                                                             \
    __builtin_amdgcn_global_load_lds(                                                     \
        (const __attribute__((address_space(1))) unsigned int*)(gptr),                    \
        (__attribute__((address_space(3))) unsigned int*)(lptr), 16, 0, 0)

// LDS-only phase barrier: does NOT drain vmcnt (prefetched global loads stay in flight)
#define LDS_BARRIER()                                                                     \
    do {                                                                                  \
        asm volatile("s_waitcnt lgkmcnt(0)" ::: "memory");                                \
        __builtin_amdgcn_s_barrier();                                                     \
    } while (0)

// any 16-bit halfword of x equal to 0xFFFF (bf16 -NaN poison)?  No false negatives.
__device__ __forceinline__ ull badw(ull x)
{
    ull y = ~x;   // poison halfword -> 0x0000
    return (y - 0x0001000100010001ull) & ~y & 0x8000800080008000ull;
}

// ---------------- f32 -> bf16 convert ----------------
__global__ void conv_kernel(const float* __restrict__ s, bf16* __restrict__ d, int n)
{
    int i = (blockIdx.x * blockDim.x + threadIdx.x) * 4;
    const int stride = gridDim.x * blockDim.x * 4;
    for (; i < n; i += stride) {
        const float4 v = *(const float4*)(s + i);
        bf16x4 o;
        o[0] = (bf16)v.x; o[1] = (bf16)v.y; o[2] = (bf16)v.z; o[3] = (bf16)v.w;
        *(bf16x4*)(d + i) = o;
    }
}

// ---------------- dense P-GEMM: P = emb @ Wih^T + b_ih (bf16 out, [32000,1024]) -------
// 128x128 tile, BK=32, double-buffered LDS, RAW s_barrier + counted vmcnt(4).
__global__ __launch_bounds__(256)
void pgemm_kernel(const bf16* __restrict__ A, const bf16* __restrict__ Wmat,
                  const float* __restrict__ bih, bf16* __restrict__ P)
{
    __shared__ __align__(16) bf16 As[2 * 128 * 32];   // 2 bufs x 8KB
    __shared__ __align__(16) bf16 Bs[2 * 128 * 32];

    const int tid = threadIdx.x;
    const int l  = tid & 63;
    const int w  = tid >> 6;
    const int wr = w >> 1, wc = w & 1;                 // wave quadrant (64x64)
    const int wg = (blockIdx.x & 7) * 250 + (blockIdx.x >> 3);   // XCD swizzle (2000%8==0)
    const int mbase = (wg >> 3) * 128;                 // 0..249
    const int nbase = (wg & 7) * 128;

    const int r0 = w * 32 + (l >> 2);                  // rows r0, r0+16
    const int csw = ((l & 3) ^ ((l >> 3) & 3)) * 16;   // swizzled 16B sub-chunk
    const char* Asrc0 = (const char*)A + (size_t)(mbase + r0) * 2048 + csw;
    const char* Asrc1 = (const char*)A + (size_t)(mbase + r0 + 16) * 2048 + csw;
    const char* Bsrc0 = (const char*)Wmat + (size_t)(nbase + r0) * 2048 + csw;
    const char* Bsrc1 = (const char*)Wmat + (size_t)(nbase + r0 + 16) * 2048 + csw;

    const int frow  = l & 15;
    const int koffE = (((l >> 4) ^ ((frow >> 1) & 3)) * 8);
    const bf16* Ard = As + (wr * 64 + frow) * 32 + koffE;
    const bf16* Brd = Bs + (wc * 64 + frow) * 32 + koffE;

    auto stage = [&](int buf, int kb) {
        bf16* As_ = As + buf * 4096 + w * 1024;        // wave-uniform dest (+lane*16)
        bf16* Bs_ = Bs + buf * 4096 + w * 1024;
        GLD_LDS16(Asrc0 + kb, As_);
        GLD_LDS16(Asrc1 + kb, As_ + 512);
        GLD_LDS16(Bsrc0 + kb, Bs_);
        GLD_LDS16(Bsrc1 + kb, Bs_ + 512);
    };

    stage(0, 0);
    stage(1, 64);

    f32x4 acc[4][4] = {};
    for (int k = 0; k < 32; ++k) {
        // wait MY 4 loads of buf k; buf k+1's 4 remain in flight across the barrier
        if (k == 31) asm volatile("s_waitcnt vmcnt(0)" ::: "memory");
        else         asm volatile("s_waitcnt vmcnt(4)" ::: "memory");
        __builtin_amdgcn_s_barrier();
        const bf16* Ab = Ard + (k & 1) * 4096;
        const bf16* Bb = Brd + (k & 1) * 4096;
        bf16x8 af[4], bfr[4];
        #pragma unroll
        for (int mt = 0; mt < 4; ++mt) af[mt]  = *(const bf16x8*)(Ab + mt * 16 * 32);
        #pragma unroll
        for (int nt = 0; nt < 4; ++nt) bfr[nt] = *(const bf16x8*)(Bb + nt * 16 * 32);
        #pragma unroll
        for (int mt = 0; mt < 4; ++mt)
            #pragma unroll
            for (int nt = 0; nt < 4; ++nt)
                acc[mt][nt] = __builtin_amdgcn_mfma_f32_16x16x32_bf16(af[mt], bfr[nt], acc[mt][nt], 0, 0, 0);
        asm volatile("s_waitcnt lgkmcnt(0)" ::: "memory");   // my ds_reads of buf k done
        __builtin_amdgcn_s_barrier();                        // all waves done -> safe restage
        if (k + 2 < 32) stage(k & 1, (k + 2) * 64);
    }

    #pragma unroll
    for (int mt = 0; mt < 4; ++mt)
        #pragma unroll
        for (int nt = 0; nt < 4; ++nt) {
            const int colg = nbase + wc * 64 + nt * 16 + frow;
            const float bi = bih[colg];
            #pragma unroll
            for (int r = 0; r < 4; ++r) {
                const int rowg = mbase + wr * 64 + mt * 16 + (l >> 4) * 4 + r;
                P[(size_t)rowg * 1024 + colg] = (bf16)(acc[mt][nt][r] + bi);
            }
        }
}

// ---------------- fused 128-step RNN: 2-group stagger, latency hidden under compute ----
// 64 blocks x 256 thr. Block (slot=bid>>2, pair=bid&3): j-cols [slot*64,+64) for groups
// gA=pair, gB=pair+4 (8 batch rows each). Whh slice LDS-resident (128KB, shared by both
// groups). Per t: {retry A_t -> Hlds -> issue B_t -> compute/store A} then same for B
// with A_{t+1} issued under B's compute. Phase barriers are LDS-only (lgkmcnt+s_barrier)
// so prefetched h-loads stay in flight. Data-valued sync (poison bf16 0xFFFF).
__global__ __launch_bounds__(256, 1)
void rnn_fused(const int* __restrict__ data, bf16* __restrict__ raw,
               const bf16* __restrict__ Whh, const bf16* __restrict__ P,
               const float* __restrict__ bhh, bf16* __restrict__ Ust)
{
    __shared__ __align__(16) bf16 Wlds[64 * 1024];       // 128KB Whh slice (swizzled)
    __shared__ __align__(16) char Hlds[8 * 2064];        // one h buffer (A/B time-shared)
    __shared__ int Tlds[2048];                           // tokens [t 128][half 2][b 8]

    const int tid    = threadIdx.x;
    const int l      = tid & 63;
    const int w      = tid >> 6;            // wave = j-tile (0..3)
    const int slot   = blockIdx.x >> 2;     // 0..15: j-slice
    const int pair   = blockIdx.x & 3;      // groups gA=pair, gB=pair+4
    const int gA     = pair;
    const int gB     = pair + 4;
    const int jbase  = slot * 64;
    const int frow   = l & 15;
    const int kchunk = l >> 4;
    const int jglob  = jbase + w * 16 + frow;
    const int rr     = frow & 7;            // real h row (8 rows duplicated to 16)

    // tokens for both groups: Tlds[t*16 + half*8 + b]
    for (int i = tid; i < 2048; i += 256) {
        const int t = i >> 4, rem = i & 15;
        const int g = (rem >> 3) ? gB : gA;
        Tlds[i] = data[t * 64 + g * 8 + (rem & 7)];
    }

    // Stage Whh j-slice (128KB) into LDS once; wave w stages its 16-col tile,
    // source pre-swizzled (kc ^= (j>>1)&3). Chunk (kk, jt=w) -> Wlds + (kk*4+w)*512.
    {
        const int jloc = l >> 2;
        const int csw  = ((l & 3) ^ ((l >> 3) & 3)) * 16;
        const char* gsrc = (const char*)Whh + (size_t)(jbase + w * 16 + jloc) * 2048 + csw;
        for (int kk = 0; kk < 32; ++kk)
            GLD_LDS16(gsrc + kk * 64, Wlds + (kk * 4 + w) * 512);
        asm volatile("s_waitcnt vmcnt(0)" ::: "memory");
    }
    __syncthreads();                       // Wlds + Tlds ready
    const float bh = bhh[jglob];

    const int ksw   = kchunk ^ ((frow >> 1) & 3);
    const bf16* wrd = Wlds + w * 512 + frow * 32 + ksw * 8;   // +kk*2048 per k-block
    const char* hrd = Hlds + rr * 2064 + kchunk * 16;         // +kk*64 per k-block

    auto retry = [&](ull* hv, const ull* src) {
        for (;;) {
            ull anybad = 0;
            #pragma unroll
            for (int i = 0; i < 8; ++i) anybad |= badw(hv[i]);
            if (!anybad) break;
            #pragma unroll
            for (int i = 0; i < 8; ++i)
                if (badw(hv[i]))
                    hv[i] = __hip_atomic_load(src + tid + i * 256,
                                              __ATOMIC_RELAXED, __HIP_MEMORY_SCOPE_AGENT);
        }
    };

    ull hvA[8], hvB[8];
    float xwA[4], xwB[4];

    // preamble: issue A_0 h-loads (raw[0] zeroed, not poisoned) + xwA gathers
    {
        const ull* srcA = (const ull*)(raw + gA * 8192);
        #pragma unroll
        for (int i = 0; i < 8; ++i)
            hvA[i] = __hip_atomic_load(srcA + tid + i * 256,
                                       __ATOMIC_RELAXED, __HIP_MEMORY_SCOPE_AGENT);
        #pragma unroll
        for (int r = 0; r < 4; ++r) {
            const int bc = (kchunk * 4 + r) & 7;
            xwA[r] = (float)P[(size_t)Tlds[bc] * 1024 + jglob];
        }
    }

    for (int t = 0; t < 128; ++t) {
        // ---------- phase A ----------
        retry(hvA, (const ull*)(raw + (size_t)t * 65536 + gA * 8192));
        LDS_BARRIER();                      // prior phase's Hlds readers done
        #pragma unroll
        for (int i = 0; i < 8; ++i)
            *(ull*)(Hlds + i * 2064 + tid * 8) = hvA[i];
        LDS_BARRIER();                      // Hlds(A) visible to all waves
        // issue B_t h-loads + xwB gathers (fly under A's compute)
        {
            const ull* srcB = (const ull*)(raw + (size_t)t * 65536 + gB * 8192);
            #pragma unroll
            for (int i = 0; i < 8; ++i)
                hvB[i] = __hip_atomic_load(srcB + tid + i * 256,
                                           __ATOMIC_RELAXED, __HIP_MEMORY_SCOPE_AGENT);
            #pragma unroll
            for (int r = 0; r < 4; ++r) {
                const int bc = (kchunk * 4 + r) & 7;
                xwB[r] = (float)P[(size_t)Tlds[t * 16 + 8 + bc] * 1024 + jglob];
            }
        }
        {   // compute + store group A
            f32x4 acc0 = {0.f,0.f,0.f,0.f}, acc1 = {0.f,0.f,0.f,0.f};
            #pragma unroll
            for (int kk = 0; kk < 32; kk += 2) {
                bf16x8 a0 = *(const bf16x8*)(hrd + kk * 64);
                bf16x8 a1 = *(const bf16x8*)(hrd + kk * 64 + 64);
                acc0 = __builtin_amdgcn_mfma_f32_16x16x32_bf16(a0, *(const bf16x8*)(wrd + kk * 2048),       acc0, 0, 0, 0);
                acc1 = __builtin_amdgcn_mfma_f32_16x16x32_bf16(a1, *(const bf16x8*)(wrd + (kk + 1) * 2048), acc1, 0, 0, 0);
            }
            bf16* rawN = raw + (size_t)(t + 1) * 65536;
            if (l < 32) {
                #pragma unroll
                for (int r = 0; r < 4; ++r) {
                    const int b = (l >> 4) * 4 + r;
                    const float V = acc0[r] + acc1[r] + bh;
                    const float h = tanhf(xwA[r] + V);
                    const size_t row = (size_t)(t * 64 + gA * 8 + b);
                    Ust[row * 1024 + jglob] = (bf16)V;
                    const bf16 hb = (bf16)h;
                    unsigned short hs = __builtin_bit_cast(unsigned short, hb);
                    unsigned short hn = (unsigned short)__shfl_down((int)hs, 1, 64);
                    if ((frow & 1) == 0) {
                        unsigned int pack = (unsigned int)hs | ((unsigned int)hn << 16);
                        unsigned int* dst = (unsigned int*)(rawN + (size_t)(gA * 8 + b) * 1024 + jglob);
                        __hip_atomic_store(dst, pack, __ATOMIC_RELAXED, __HIP_MEMORY_SCOPE_AGENT);
                    }
                }
            }
        }
        // ---------- phase B ----------
        retry(hvB, (const ull*)(raw + (size_t)t * 65536 + gB * 8192));
        LDS_BARRIER();                      // A's Hlds readers done
        #pragma unroll
        for (int i = 0; i < 8; ++i)
            *(ull*)(Hlds + i * 2064 + tid * 8) = hvB[i];
        LDS_BARRIER();                      // Hlds(B) visible
        // issue A_{t+1} h-loads + xwA gathers (fly under B's compute)
        if (t < 127) {
            const ull* srcA = (const ull*)(raw + (size_t)(t + 1) * 65536 + gA * 8192);
            #pragma unroll
            for (int i = 0; i < 8; ++i)
                hvA[i] = __hip_atomic_load(srcA + tid + i * 256,
                                           __ATOMIC_RELAXED, __HIP_MEMORY_SCOPE_AGENT);
            #pragma unroll
            for (int r = 0; r < 4; ++r) {
                const int bc = (kchunk * 4 + r) & 7;
                xwA[r] = (float)P[(size_t)Tlds[(t + 1) * 16 + bc] * 1024 + jglob];
            }
        }
        {   // compute + store group B
            f32x4 acc0 = {0.f,0.f,0.f,0.f}, acc1 = {0.f,0.f,0.f,0.f};
            #pragma unroll
            for (int kk = 0; kk < 32; kk += 2) {
                bf16x8 a0 = *(const bf16x8*)(hrd + kk * 64);
                bf16x8 a1 = *(const bf16x8*)(hrd + kk * 64 + 64);
                acc0 = __builtin_amdgcn_mfma_f32_16x16x32_bf16(a0, *(const bf16x8*)(wrd + kk * 2048),       acc0, 0, 0, 0);
                acc1 = __builtin_amdgcn_mfma_f32_16x16x32_bf16(a1, *(const bf16x8*)(wrd + (kk + 1) * 2048), acc1, 0, 0, 0);
            }
            bf16* rawN = raw + (size_t)(t + 1) * 65536;
            if (l < 32) {
                #pragma unroll
                for (int r = 0; r < 4; ++r) {
                    const int b = (l >> 4) * 4 + r;
                    const float V = acc0[r] + acc1[r] + bh;
                    const float h = tanhf(xwB[r] + V);
                    const size_t row = (size_t)(t * 64 + gB * 8 + b);
                    Ust[row * 1024 + jglob] = (bf16)V;
                    const bf16 hb = (bf16)h;
                    unsigned short hs = __builtin_bit_cast(unsigned short, hb);
                    unsigned short hn = (unsigned short)__shfl_down((int)hs, 1, 64);
                    if ((frow & 1) == 0) {
                        unsigned int pack = (unsigned int)hs | ((unsigned int)hn << 16);
                        unsigned int* dst = (unsigned int*)(rawN + (size_t)(gB * 8 + b) * 1024 + jglob);
                        __hip_atomic_store(dst, pack, __ATOMIC_RELAXED, __HIP_MEMORY_SCOPE_AGENT);
                    }
                }
            }
        }
    }
}

// ---------------- pos term: (65/128) * sum (raw[t]-raw[t+1]+eps)^2 ----------------
__global__ void pos_kernel(const bf16* __restrict__ raw, float* __restrict__ lacc)
{
    float s = 0.f;
    const int NV = (128 * 64 * 1024) / 8;
    for (int i = blockIdx.x * blockDim.x + threadIdx.x; i < NV; i += gridDim.x * blockDim.x) {
        bf16x8 a = *(const bf16x8*)(raw + (size_t)i * 8);
        bf16x8 b = *(const bf16x8*)(raw + (size_t)i * 8 + 65536);
        #pragma unroll
        for (int j = 0; j < 8; ++j) {
            const float d = (float)a[j] - (float)b[j] + EPSC;
            s += d * d;
        }
    }
    #pragma unroll
    for (int off = 32; off > 0; off >>= 1) s += __shfl_down(s, off, 64);
    if ((threadIdx.x & 63) == 0) atomicAdd(lacc, s * (TEMPC / 128.f));
}

// ---------------- neg term: per row r, log(sum_s exp(-clip(||prev - tanh(P+U)||^2))) ---
__global__ __launch_bounds__(256)
void neg_kernel(const int* __restrict__ samples, const bf16* __restrict__ P,
                const bf16* __restrict__ Ust, const bf16* __restrict__ raw,
                float* __restrict__ lacc)
{
    const int l = threadIdx.x & 63;
    const int r = blockIdx.x * 4 + (threadIdx.x >> 6);   // row 0..8191
    const bf16* u  = Ust + (size_t)r * 1024;
    const bf16* pv = raw + (size_t)r * 1024;

    float uf[16], vf[16];
    {
        bf16x8 u0 = *(const bf16x8*)(u + l * 8);
        bf16x8 u1 = *(const bf16x8*)(u + 512 + l * 8);
        bf16x8 v0 = *(const bf16x8*)(pv + l * 8);
        bf16x8 v1 = *(const bf16x8*)(pv + 512 + l * 8);
        #pragma unroll
        for (int i = 0; i < 8; ++i) {
            uf[i] = (float)u0[i]; uf[8 + i] = (float)u1[i];
            vf[i] = (float)v0[i]; vf[8 + i] = (float)v1[i];
        }
    }

    float se = 0.f;
    #pragma unroll
    for (int s = 0; s < 10; ++s) {
        const int tok = samples[s * 8192 + r];
        const bf16* pr = P + (size_t)tok * 1024;
        bf16x8 p0 = *(const bf16x8*)(pr + l * 8);
        bf16x8 p1 = *(const bf16x8*)(pr + 512 + l * 8);
        float d2 = 0.f;
        #pragma unroll
        for (int i = 0; i < 8; ++i) {
            const float o0 = tanhf((float)p0[i] + uf[i]);
            const float d0 = vf[i] - o0 + EPSC;
            d2 += d0 * d0;
            const float o1 = tanhf((float)p1[i] + uf[8 + i]);
            const float d1 = vf[8 + i] - o1 + EPSC;
            d2 += d1 * d1;
        }
        #pragma unroll
        for (int off = 1; off < 64; off <<= 1)
            d2 += __shfl_xor(d2, off, 64);
        se += expf(-fminf(d2, 0.01f));               // d2 >= 0 already
    }
    if (l == 0) atomicAdd(lacc, logf(se * (1.f / 8192.f) + EPSC));
}

// ---------------- finalize ----------------
__global__ void fin_kernel(const float* __restrict__ lacc, float* __restrict__ out)
{
    if (threadIdx.x == 0) out[0] = lacc[0];
}

extern "C" void kernel_launch(void* const* d_in, const int* in_sizes, int n_in,
                              void* d_out, int out_size, void* d_ws, size_t ws_size,
                              hipStream_t stream)
{
    const int*   data    = (const int*)d_in[0];   // [128*64]
    const int*   samples = (const int*)d_in[1];   // [10*8192]
    const float* emb     = (const float*)d_in[2]; // [32000*1024]
    const float* Wih     = (const float*)d_in[3]; // [1024*1024]
    const float* bih     = (const float*)d_in[4]; // [1024]
    const float* Whh     = (const float*)d_in[5]; // [1024*1024]
    const float* bhh     = (const float*)d_in[6]; // [1024]

    char* ws = (char*)d_ws;
    size_t off = 0;
    auto alloc = [&](size_t bytes) { void* p = ws + off; off += (bytes + 255) & ~(size_t)255; return p; };
    bf16*  emb_b = (bf16*)alloc((size_t)32000 * 1024 * 2);
    bf16*  Wih_b = (bf16*)alloc((size_t)1024 * 1024 * 2);
    bf16*  Whh_b = (bf16*)alloc((size_t)1024 * 1024 * 2);
    bf16*  P     = (bf16*)alloc((size_t)32000 * 1024 * 2);
    bf16*  Ust   = (bf16*)alloc((size_t)8192 * 1024 * 2);
    bf16*  raw   = (bf16*)alloc((size_t)129 * 64 * 1024 * 2);
    float* lacc  = (float*)alloc(256);

    // poison ALL of raw with bf16 -NaN (0xFFFF), then zero h0 (raw[0])
    hipMemsetAsync(raw, 0xFF, (size_t)129 * 64 * 1024 * 2, stream);
    hipMemsetAsync(raw, 0, 64 * 1024 * 2, stream);
    hipMemsetAsync(lacc, 0, 256, stream);

    conv_kernel<<<2048, 256, 0, stream>>>(emb, emb_b, 32000 * 1024);
    conv_kernel<<<512, 256, 0, stream>>>(Wih, Wih_b, 1024 * 1024);
    conv_kernel<<<512, 256, 0, stream>>>(Whh, Whh_b, 1024 * 1024);

    // full-vocab projection table: P = emb @ Wih^T + b_ih
    pgemm_kernel<<<2000, 256, 0, stream>>>(emb_b, Wih_b, bih, P);

    // 128 RNN steps (2-group stagger; data-valued polling)
    rnn_fused<<<64, 256, 0, stream>>>(data, raw, Whh_b, P, bhh, Ust);

    // pos term
    pos_kernel<<<512, 256, 0, stream>>>(raw, lacc);

    // neg term: gather-elementwise over samples (no GEMM)
    neg_kernel<<<2048, 256, 0, stream>>>(samples, P, Ust, raw, lacc);

    fin_kernel<<<1, 64, 0, stream>>>(lacc, (float*)d_out);
}

// Round 13
// 665.307 us; speedup vs baseline: 1.2533x; 1.2533x over previous
//
#include <hip/hip_runtime.h>
#include <hip/hip_bf16.h>
#include <cmath>

typedef __bf16 bf16;
typedef __attribute__((ext_vector_type(8))) __bf16 bf16x8;
typedef __attribute__((ext_vector_type(4))) __bf16 bf16x4;
typedef __attribute__((ext_vector_type(4))) float f32x4;
typedef unsigned long long ull;

#define TEMPC 65.0f
#define EPSC 1e-6f

#define GLD_LDS16(gptr, lptr)                                                             \
    __builtin_amdgcn_global_load_lds(                                                     \
        (const __attribute__((address_space(1))) unsigned int*)(gptr),                    \
        (__attribute__((address_space(3))) unsigned int*)(lptr), 16, 0, 0)

// ---------------- f32 -> bf16 convert ----------------
__global__ void conv_kernel(const float* __restrict__ s, bf16* __restrict__ d, int n)
{
    int i = (blockIdx.x * blockDim.x + threadIdx.x) * 4;
    const int stride = gridDim.x * blockDim.x * 4;
    for (; i < n; i += stride) {
        const float4 v = *(const float4*)(s + i);
        bf16x4 o;
        o[0] = (bf16)v.x; o[1] = (bf16)v.y; o[2] = (bf16)v.z; o[3] = (bf16)v.w;
        *(bf16x4*)(d + i) = o;
    }
}

// ---------------- gemm0: XWb = emb[data] @ Wih^T + bih (bf16, [8192,1024]) ------------
// 128x128 tile, BK=32, dbuf LDS, raw s_barrier + counted vmcnt(4), XOR swizzle.
__global__ __launch_bounds__(256)
void gemm0_kernel(const int* __restrict__ idx, const bf16* __restrict__ emb,
                  const bf16* __restrict__ Wmat, const float* __restrict__ bih,
                  bf16* __restrict__ XWout)
{
    __shared__ __align__(16) bf16 As[2 * 128 * 32];
    __shared__ __align__(16) bf16 Bs[2 * 128 * 32];

    const int tid = threadIdx.x;
    const int l  = tid & 63;
    const int w  = tid >> 6;
    const int wr = w >> 1, wc = w & 1;
    const int wg = (blockIdx.x & 7) * 64 + (blockIdx.x >> 3);   // XCD swizzle (512%8==0)
    const int mbase = (wg >> 3) * 128;
    const int nbase = (wg & 7) * 128;

    const int r0 = w * 32 + (l >> 2);
    const int csw = ((l & 3) ^ ((l >> 3) & 3)) * 16;
    const char* Asrc0 = (const char*)emb + (size_t)idx[mbase + r0] * 2048 + csw;
    const char* Asrc1 = (const char*)emb + (size_t)idx[mbase + r0 + 16] * 2048 + csw;
    const char* Bsrc0 = (const char*)Wmat + (size_t)(nbase + r0) * 2048 + csw;
    const char* Bsrc1 = (const char*)Wmat + (size_t)(nbase + r0 + 16) * 2048 + csw;

    const int frow  = l & 15;
    const int koffE = (((l >> 4) ^ ((frow >> 1) & 3)) * 8);
    const bf16* Ard = As + (wr * 64 + frow) * 32 + koffE;
    const bf16* Brd = Bs + (wc * 64 + frow) * 32 + koffE;

    auto stage = [&](int buf, int kb) {
        bf16* As_ = As + buf * 4096 + w * 1024;
        bf16* Bs_ = Bs + buf * 4096 + w * 1024;
        GLD_LDS16(Asrc0 + kb, As_);
        GLD_LDS16(Asrc1 + kb, As_ + 512);
        GLD_LDS16(Bsrc0 + kb, Bs_);
        GLD_LDS16(Bsrc1 + kb, Bs_ + 512);
    };

    stage(0, 0);
    stage(1, 64);

    f32x4 acc[4][4] = {};
    for (int k = 0; k < 32; ++k) {
        if (k == 31) asm volatile("s_waitcnt vmcnt(0)" ::: "memory");
        else         asm volatile("s_waitcnt vmcnt(4)" ::: "memory");
        __builtin_amdgcn_s_barrier();
        const bf16* Ab = Ard + (k & 1) * 4096;
        const bf16* Bb = Brd + (k & 1) * 4096;
        bf16x8 af[4], bfr[4];
        #pragma unroll
        for (int mt = 0; mt < 4; ++mt) af[mt]  = *(const bf16x8*)(Ab + mt * 16 * 32);
        #pragma unroll
        for (int nt = 0; nt < 4; ++nt) bfr[nt] = *(const bf16x8*)(Bb + nt * 16 * 32);
        #pragma unroll
        for (int mt = 0; mt < 4; ++mt)
            #pragma unroll
            for (int nt = 0; nt < 4; ++nt)
                acc[mt][nt] = __builtin_amdgcn_mfma_f32_16x16x32_bf16(af[mt], bfr[nt], acc[mt][nt], 0, 0, 0);
        asm volatile("s_waitcnt lgkmcnt(0)" ::: "memory");
        __builtin_amdgcn_s_barrier();
        if (k + 2 < 32) stage(k & 1, (k + 2) * 64);
    }

    #pragma unroll
    for (int mt = 0; mt < 4; ++mt)
        #pragma unroll
        for (int nt = 0; nt < 4; ++nt) {
            const int colg = nbase + wc * 64 + nt * 16 + frow;
            const float bi = bih[colg];
            #pragma unroll
            for (int r = 0; r < 4; ++r) {
                const int rowg = mbase + wr * 64 + mt * 16 + (l >> 4) * 4 + r;
                XWout[(size_t)rowg * 1024 + colg] = (bf16)(acc[mt][nt][r] + bi);
            }
        }
}

// ---------------- FUSED: RNN (blocks 0-127) + dense P-GEMM (blocks 128-2127) ----------
// No cross-role fences or waits: disjoint buffers. rnn = R9 structure (440us proven);
// pgemm fills the 128 CUs the rnn doesn't occupy. One 144KB LDS pool -> 1 block/CU.
__global__ __launch_bounds__(256, 1)
void fused_kernel(const bf16* __restrict__ emb, const bf16* __restrict__ Wih,
                  const float* __restrict__ bih, bf16* __restrict__ P,
                  bf16* __restrict__ raw, const bf16* __restrict__ Whh,
                  const bf16* __restrict__ XWb, const float* __restrict__ bhh,
                  bf16* __restrict__ Ust, int* __restrict__ cnt)
{
    __shared__ __align__(16) char pool[147584];   // rnn: 128K Wlds + 16.5K Hlds; pgemm: 32K
    const int tid = threadIdx.x;
    const int l   = tid & 63;
    const int w   = tid >> 6;
    const int id  = blockIdx.x;

    if (id < 128) {
        // ================= RNN role (R9 structure) =================
        bf16* Wlds = (bf16*)pool;                    // 128KB
        char* Hlds = pool + 131072;                  // 8 rows x 2064B
        const int group  = id & 7;                   // batch group (XCD-aligned heuristic)
        const int slot   = id >> 3;                  // 0..15: j-slice
        const int jbase  = slot * 64;
        const int frow   = l & 15;
        const int kchunk = l >> 4;
        const int jglob  = jbase + w * 16 + frow;
        const int rr     = frow & 7;

        {   // stage Whh j-slice (128KB), source pre-swizzled (kc ^= (j>>1)&3)
            const int jloc = l >> 2;
            const int csw  = ((l & 3) ^ ((l >> 3) & 3)) * 16;
            const char* gsrc = (const char*)Whh + (size_t)(jbase + w * 16 + jloc) * 2048 + csw;
            for (int kk = 0; kk < 32; ++kk)
                GLD_LDS16(gsrc + kk * 64, Wlds + (kk * 4 + w) * 512);
            asm volatile("s_waitcnt vmcnt(0)" ::: "memory");
            __syncthreads();
        }
        const float bh = bhh[jglob];

        const int ksw   = kchunk ^ ((frow >> 1) & 3);
        const bf16* wrd = Wlds + w * 512 + frow * 32 + ksw * 8;   // +kk*2048 per k-block
        const char* hrd = Hlds + rr * 2064 + kchunk * 16;         // +kk*64 per k-block

        for (int t = 0; t < 128; ++t) {
            if (t > 0) {
                if (tid < 4)                 // parallel poll: 4 sub-counters x 4 adds
                    while (__hip_atomic_load(&cnt[((t * 8 + group) * 4 + tid) * 32],
                                             __ATOMIC_RELAXED, __HIP_MEMORY_SCOPE_AGENT) < 4)
                        __builtin_amdgcn_s_sleep(1);
                __syncthreads();
            }
            // cooperative coherent fetch of group h_t (16KB): 256 thr x 8 x 8B
            const ull* hsrc8 = (const ull*)(raw + (size_t)t * 65536 + group * 8192);
            ull hv[8];
            #pragma unroll
            for (int i = 0; i < 8; ++i)
                hv[i] = __hip_atomic_load(hsrc8 + tid + i * 256,
                                          __ATOMIC_RELAXED, __HIP_MEMORY_SCOPE_AGENT);
            float xw[4];
            #pragma unroll
            for (int r = 0; r < 4; ++r) {
                const int bc = (kchunk * 4 + r) & 7;
                xw[r] = (float)XWb[(size_t)(t * 64 + group * 8 + bc) * 1024 + jglob];
            }
            #pragma unroll
            for (int i = 0; i < 8; ++i)
                *(ull*)(Hlds + i * 2064 + tid * 8) = hv[i];
            __syncthreads();

            f32x4 acc0 = {0.f,0.f,0.f,0.f}, acc1 = {0.f,0.f,0.f,0.f};
            #pragma unroll
            for (int kk = 0; kk < 32; kk += 2) {
                bf16x8 a0 = *(const bf16x8*)(hrd + kk * 64);
                bf16x8 a1 = *(const bf16x8*)(hrd + kk * 64 + 64);
                acc0 = __builtin_amdgcn_mfma_f32_16x16x32_bf16(a0, *(const bf16x8*)(wrd + kk * 2048),       acc0, 0, 0, 0);
                acc1 = __builtin_amdgcn_mfma_f32_16x16x32_bf16(a1, *(const bf16x8*)(wrd + (kk + 1) * 2048), acc1, 0, 0, 0);
            }

            bf16* rawN = raw + (size_t)(t + 1) * 65536;
            if (l < 32) {                            // rows 0-7 real
                #pragma unroll
                for (int r = 0; r < 4; ++r) {
                    const int b = (l >> 4) * 4 + r;
                    const float V = acc0[r] + acc1[r] + bh;          // h @ Whh^T + b_hh
                    const float h = tanhf(xw[r] + V);                // xw holds + b_ih
                    const size_t row = (size_t)(t * 64 + group * 8 + b);
                    Ust[row * 1024 + jglob] = (bf16)V;               // hiddens_U (no b_ih)
                    const bf16 hb = (bf16)h;
                    unsigned short hs = __builtin_bit_cast(unsigned short, hb);
                    unsigned short hn = (unsigned short)__shfl_down((int)hs, 1, 64);
                    if ((frow & 1) == 0) {                           // pack 2 cols -> 4B
                        unsigned int pack = (unsigned int)hs | ((unsigned int)hn << 16);
                        unsigned int* dst = (unsigned int*)(rawN + (size_t)(group * 8 + b) * 1024 + jglob);
                        __hip_atomic_store(dst, pack, __ATOMIC_RELAXED, __HIP_MEMORY_SCOPE_AGENT);
                    }
                }
            }
            if (t < 127) {
                __syncthreads();                     // store acks drained
                if (tid == 0)
                    __hip_atomic_fetch_add(&cnt[(((t + 1) * 8 + group) * 4 + (slot & 3)) * 32], 1,
                                           __ATOMIC_RELAXED, __HIP_MEMORY_SCOPE_AGENT);
            }
        }
    } else {
        // ================= P-GEMM role: one 128x128 tile of P = emb @ Wih^T + bih =====
        bf16* As = (bf16*)pool;                      // 16KB (2 bufs)
        bf16* Bs = (bf16*)(pool + 16384);            // 16KB
        const int q  = id - 128;                     // 0..1999
        const int wg = (q & 7) * 250 + (q >> 3);     // XCD swizzle (2000%8==0)
        const int mbase = (wg >> 3) * 128;           // 0..249
        const int nbase = (wg & 7) * 128;
        const int wr = w >> 1, wc = w & 1;

        const int r0 = w * 32 + (l >> 2);
        const int csw = ((l & 3) ^ ((l >> 3) & 3)) * 16;
        const char* Asrc0 = (const char*)emb + (size_t)(mbase + r0) * 2048 + csw;
        const char* Asrc1 = (const char*)emb + (size_t)(mbase + r0 + 16) * 2048 + csw;
        const char* Bsrc0 = (const char*)Wih + (size_t)(nbase + r0) * 2048 + csw;
        const char* Bsrc1 = (const char*)Wih + (size_t)(nbase + r0 + 16) * 2048 + csw;

        const int frow  = l & 15;
        const int koffE = (((l >> 4) ^ ((frow >> 1) & 3)) * 8);
        const bf16* Ard = As + (wr * 64 + frow) * 32 + koffE;
        const bf16* Brd = Bs + (wc * 64 + frow) * 32 + koffE;

        auto stage = [&](int buf, int kb) {
            bf16* As_ = As + buf * 4096 + w * 1024;
            bf16* Bs_ = Bs + buf * 4096 + w * 1024;
            GLD_LDS16(Asrc0 + kb, As_);
            GLD_LDS16(Asrc1 + kb, As_ + 512);
            GLD_LDS16(Bsrc0 + kb, Bs_);
            GLD_LDS16(Bsrc1 + kb, Bs_ + 512);
        };

        stage(0, 0);
        stage(1, 64);

        f32x4 acc[4][4] = {};
        for (int k = 0; k < 32; ++k) {
            if (k == 31) asm volatile("s_waitcnt vmcnt(0)" ::: "memory");
            else         asm volatile("s_waitcnt vmcnt(4)" ::: "memory");
            __builtin_amdgcn_s_barrier();
            const bf16* Ab = Ard + (k & 1) * 4096;
            const bf16* Bb = Brd + (k & 1) * 4096;
            bf16x8 af[4], bfr[4];
            #pragma unroll
            for (int mt = 0; mt < 4; ++mt) af[mt]  = *(const bf16x8*)(Ab + mt * 16 * 32);
            #pragma unroll
            for (int nt = 0; nt < 4; ++nt) bfr[nt] = *(const bf16x8*)(Bb + nt * 16 * 32);
            #pragma unroll
            for (int mt = 0; mt < 4; ++mt)
                #pragma unroll
                for (int nt = 0; nt < 4; ++nt)
                    acc[mt][nt] = __builtin_amdgcn_mfma_f32_16x16x32_bf16(af[mt], bfr[nt], acc[mt][nt], 0, 0, 0);
            asm volatile("s_waitcnt lgkmcnt(0)" ::: "memory");
            __builtin_amdgcn_s_barrier();
            if (k + 2 < 32) stage(k & 1, (k + 2) * 64);
        }

        #pragma unroll
        for (int mt = 0; mt < 4; ++mt)
            #pragma unroll
            for (int nt = 0; nt < 4; ++nt) {
                const int colg = nbase + wc * 64 + nt * 16 + frow;
                const float bi = bih[colg];
                #pragma unroll
                for (int r = 0; r < 4; ++r) {
                    const int rowg = mbase + wr * 64 + mt * 16 + (l >> 4) * 4 + r;
                    P[(size_t)rowg * 1024 + colg] = (bf16)(acc[mt][nt][r] + bi);
                }
            }
    }
}

// ---------------- pos term: (65/128) * sum (raw[t]-raw[t+1]+eps)^2 ----------------
__global__ void pos_kernel(const bf16* __restrict__ raw, float* __restrict__ lacc)
{
    float s = 0.f;
    const int NV = (128 * 64 * 1024) / 8;
    for (int i = blockIdx.x * blockDim.x + threadIdx.x; i < NV; i += gridDim.x * blockDim.x) {
        bf16x8 a = *(const bf16x8*)(raw + (size_t)i * 8);
        bf16x8 b = *(const bf16x8*)(raw + (size_t)i * 8 + 65536);
        #pragma unroll
        for (int j = 0; j < 8; ++j) {
            const float d = (float)a[j] - (float)b[j] + EPSC;
            s += d * d;
        }
    }
    #pragma unroll
    for (int off = 32; off > 0; off >>= 1) s += __shfl_down(s, off, 64);
    if ((threadIdx.x & 63) == 0) atomicAdd(lacc, s * (TEMPC / 128.f));
}

// ---------------- neg term: per row r, log(sum_s exp(-clip(||prev - tanh(P+U)||^2))) ---
__global__ __launch_bounds__(256)
void neg_kernel(const int* __restrict__ samples, const bf16* __restrict__ P,
                const bf16* __restrict__ Ust, const bf16* __restrict__ raw,
                float* __restrict__ lacc)
{
    const int l = threadIdx.x & 63;
    const int r = blockIdx.x * 4 + (threadIdx.x >> 6);   // row 0..8191
    const bf16* u  = Ust + (size_t)r * 1024;
    const bf16* pv = raw + (size_t)r * 1024;

    float uf[16], vf[16];
    {
        bf16x8 u0 = *(const bf16x8*)(u + l * 8);
        bf16x8 u1 = *(const bf16x8*)(u + 512 + l * 8);
        bf16x8 v0 = *(const bf16x8*)(pv + l * 8);
        bf16x8 v1 = *(const bf16x8*)(pv + 512 + l * 8);
        #pragma unroll
        for (int i = 0; i < 8; ++i) {
            uf[i] = (float)u0[i]; uf[8 + i] = (float)u1[i];
            vf[i] = (float)v0[i]; vf[8 + i] = (float)v1[i];
        }
    }

    float se = 0.f;
    #pragma unroll
    for (int s = 0; s < 10; ++s) {
        const int tok = samples[s * 8192 + r];
        const bf16* pr = P + (size_t)tok * 1024;
        bf16x8 p0 = *(const bf16x8*)(pr + l * 8);
        bf16x8 p1 = *(const bf16x8*)(pr + 512 + l * 8);
        float d2 = 0.f;
        #pragma unroll
        for (int i = 0; i < 8; ++i) {
            const float o0 = tanhf((float)p0[i] + uf[i]);
            const float d0 = vf[i] - o0 + EPSC;
            d2 += d0 * d0;
            const float o1 = tanhf((float)p1[i] + uf[8 + i]);
            const float d1 = vf[8 + i] - o1 + EPSC;
            d2 += d1 * d1;
        }
        #pragma unroll
        for (int off = 1; off < 64; off <<= 1)
            d2 += __shfl_xor(d2, off, 64);
        se += expf(-fminf(d2, 0.01f));               // d2 >= 0 already
    }
    if (l == 0) atomicAdd(lacc, logf(se * (1.f / 8192.f) + EPSC));
}

// ---------------- finalize ----------------
__global__ void fin_kernel(const float* __restrict__ lacc, float* __restrict__ out)
{
    if (threadIdx.x == 0) out[0] = lacc[0];
}

extern "C" void kernel_launch(void* const* d_in, const int* in_sizes, int n_in,
                              void* d_out, int out_size, void* d_ws, size_t ws_size,
                              hipStream_t stream)
{
    const int*   data    = (const int*)d_in[0];   // [128*64]
    const int*   samples = (const int*)d_in[1];   // [10*8192]
    const float* emb     = (const float*)d_in[2]; // [32000*1024]
    const float* Wih     = (const float*)d_in[3]; // [1024*1024]
    const float* bih     = (const float*)d_in[4]; // [1024]
    const float* Whh     = (const float*)d_in[5]; // [1024*1024]
    const float* bhh     = (const float*)d_in[6]; // [1024]

    char* ws = (char*)d_ws;
    size_t off = 0;
    auto alloc = [&](size_t bytes) { void* p = ws + off; off += (bytes + 255) & ~(size_t)255; return p; };
    bf16*  emb_b = (bf16*)alloc((size_t)32000 * 1024 * 2);
    bf16*  Wih_b = (bf16*)alloc((size_t)1024 * 1024 * 2);
    bf16*  Whh_b = (bf16*)alloc((size_t)1024 * 1024 * 2);
    bf16*  P     = (bf16*)alloc((size_t)32000 * 1024 * 2);
    bf16*  XWb   = (bf16*)alloc((size_t)8192 * 1024 * 2);
    bf16*  Ust   = (bf16*)alloc((size_t)8192 * 1024 * 2);
    bf16*  raw   = (bf16*)alloc((size_t)129 * 64 * 1024 * 2);
    float* lacc  = (float*)alloc(256);
    int*   cnt   = (int*)alloc(524288);

    hipMemsetAsync(raw, 0, 64 * 1024 * 2, stream);    // h0 = 0 (raw[0])
    hipMemsetAsync(lacc, 0, 256, stream);
    hipMemsetAsync(cnt,  0, 524288, stream);          // split step-barrier counters

    conv_kernel<<<2048, 256, 0, stream>>>(emb, emb_b, 32000 * 1024);
    conv_kernel<<<512, 256, 0, stream>>>(Wih, Wih_b, 1024 * 1024);
    conv_kernel<<<512, 256, 0, stream>>>(Whh, Whh_b, 1024 * 1024);

    // XWb = emb[data] @ Wih^T + bih (small gather GEMM, feeds the RNN)
    gemm0_kernel<<<512, 256, 0, stream>>>(data, emb_b, Wih_b, bih, XWb);

    // FUSED: 128 RNN blocks + 2000 P-GEMM tiles, fully independent roles
    fused_kernel<<<2128, 256, 0, stream>>>(emb_b, Wih_b, bih, P,
                                           raw, Whh_b, XWb, bhh, Ust, cnt);

    // pos term
    pos_kernel<<<512, 256, 0, stream>>>(raw, lacc);

    // neg term: gather-elementwise over samples (no GEMM)
    neg_kernel<<<2048, 256, 0, stream>>>(samples, P, Ust, raw, lacc);

    fin_kernel<<<1, 64, 0, stream>>>(lacc, (float*)d_out);
}

// Round 14
// 577.221 us; speedup vs baseline: 1.4446x; 1.1526x over previous
//
#include <hip/hip_runtime.h>
#include <hip/hip_bf16.h>
#include <cmath>

typedef __bf16 bf16;
typedef __attribute__((ext_vector_type(8))) __bf16 bf16x8;
typedef __attribute__((ext_vector_type(4))) __bf16 bf16x4;
typedef __attribute__((ext_vector_type(4))) float f32x4;
typedef unsigned long long ull;

#define TEMPC 65.0f
#define EPSC 1e-6f

#define GLD_LDS16(gptr, lptr)                                                             \
    __builtin_amdgcn_global_load_lds(                                                     \
        (const __attribute__((address_space(1))) unsigned int*)(gptr),                    \
        (__attribute__((address_space(3))) unsigned int*)(lptr), 16, 0, 0)

// ---------------- one-shot f32 -> bf16 convert: emb, Wih, Whh ----------------
__global__ void conv3_kernel(const float* __restrict__ e, bf16* __restrict__ eb,
                             const float* __restrict__ a, bf16* __restrict__ ab,
                             const float* __restrict__ b, bf16* __restrict__ bb)
{
    const int base   = (blockIdx.x * blockDim.x + threadIdx.x) * 4;
    const int stride = gridDim.x * blockDim.x * 4;
    for (int i = base; i < 32000 * 1024; i += stride) {
        const float4 v = *(const float4*)(e + i);
        bf16x4 o; o[0]=(bf16)v.x; o[1]=(bf16)v.y; o[2]=(bf16)v.z; o[3]=(bf16)v.w;
        *(bf16x4*)(eb + i) = o;
    }
    for (int i = base; i < 1024 * 1024; i += stride) {
        const float4 v = *(const float4*)(a + i);
        bf16x4 o; o[0]=(bf16)v.x; o[1]=(bf16)v.y; o[2]=(bf16)v.z; o[3]=(bf16)v.w;
        *(bf16x4*)(ab + i) = o;
    }
    for (int i = base; i < 1024 * 1024; i += stride) {
        const float4 v = *(const float4*)(b + i);
        bf16x4 o; o[0]=(bf16)v.x; o[1]=(bf16)v.y; o[2]=(bf16)v.z; o[3]=(bf16)v.w;
        *(bf16x4*)(bb + i) = o;
    }
}

// ---------------- FUSED: RNN (0-127) + gemm0/XWb (128-639) + P-GEMM (640-2639) --------
// No cross-role fences. XWb is 0xFF-poisoned; gemm0 tiles write it with packed 4B
// agent-atomic stores (write-through); RNN polls xw values for poison (retry deferred
// past the MFMA). pos term accumulated inline by the RNN role.
__global__ __launch_bounds__(256, 1)
void fused_kernel(const int* __restrict__ data, const bf16* __restrict__ emb,
                  const bf16* __restrict__ Wih, const float* __restrict__ bih,
                  bf16* __restrict__ P, bf16* __restrict__ raw,
                  const bf16* __restrict__ Whh, bf16* __restrict__ XWb,
                  const float* __restrict__ bhh, bf16* __restrict__ Ust,
                  int* __restrict__ cnt, float* __restrict__ lacc)
{
    __shared__ __align__(16) char pool[147584];   // rnn: 128K Wlds + 16.5K Hlds; gemm: 32K
    const int tid = threadIdx.x;
    const int l   = tid & 63;
    const int w   = tid >> 6;
    const int id  = blockIdx.x;

    if (id < 128) {
        // ================= RNN role (R9 sync structure, xw poison-poll, inline pos) ====
        bf16* Wlds = (bf16*)pool;                    // 128KB
        char* Hlds = pool + 131072;                  // 8 rows x 2064B
        const int group  = id & 7;
        const int slot   = id >> 3;                  // 0..15: j-slice
        const int jbase  = slot * 64;
        const int frow   = l & 15;
        const int kchunk = l >> 4;
        const int jglob  = jbase + w * 16 + frow;
        const int rr     = frow & 7;

        {   // stage Whh j-slice (128KB), source pre-swizzled (kc ^= (j>>1)&3)
            const int jloc = l >> 2;
            const int csw  = ((l & 3) ^ ((l >> 3) & 3)) * 16;
            const char* gsrc = (const char*)Whh + (size_t)(jbase + w * 16 + jloc) * 2048 + csw;
            for (int kk = 0; kk < 32; ++kk)
                GLD_LDS16(gsrc + kk * 64, Wlds + (kk * 4 + w) * 512);
            asm volatile("s_waitcnt vmcnt(0)" ::: "memory");
            __syncthreads();
        }
        const float bh = bhh[jglob];

        const int ksw   = kchunk ^ ((frow >> 1) & 3);
        const bf16* wrd = Wlds + w * 512 + frow * 32 + ksw * 8;   // +kk*2048 per k-block
        const char* hrd = Hlds + rr * 2064 + kchunk * 16;         // +kk*64 per k-block
        const int jpair = jglob & ~1;
        float posacc = 0.f;

        for (int t = 0; t < 128; ++t) {
            if (t > 0) {
                if (tid < 4)                 // parallel poll: 4 sub-counters x 4 adds
                    while (__hip_atomic_load(&cnt[((t * 8 + group) * 4 + tid) * 32],
                                             __ATOMIC_RELAXED, __HIP_MEMORY_SCOPE_AGENT) < 4)
                        __builtin_amdgcn_s_sleep(1);
                __syncthreads();
            }
            // cooperative coherent fetch of group h_t (16KB): 256 thr x 8 x 8B
            const ull* hsrc8 = (const ull*)(raw + (size_t)t * 65536 + group * 8192);
            ull hv[8];
            #pragma unroll
            for (int i = 0; i < 8; ++i)
                hv[i] = __hip_atomic_load(hsrc8 + tid + i * 256,
                                          __ATOMIC_RELAXED, __HIP_MEMORY_SCOPE_AGENT);
            // xw: coherent 4B loads (pair of bf16 cols); poison-retry deferred past MFMA
            unsigned int xww[4];
            #pragma unroll
            for (int r = 0; r < 4; ++r) {
                const int bc = (kchunk * 4 + r) & 7;
                const size_t row = (size_t)(t * 64 + group * 8 + bc);
                xww[r] = __hip_atomic_load((const unsigned int*)(XWb + row * 1024 + jpair),
                                           __ATOMIC_RELAXED, __HIP_MEMORY_SCOPE_AGENT);
            }
            #pragma unroll
            for (int i = 0; i < 8; ++i)
                *(ull*)(Hlds + i * 2064 + tid * 8) = hv[i];
            __syncthreads();

            f32x4 acc0 = {0.f,0.f,0.f,0.f}, acc1 = {0.f,0.f,0.f,0.f};
            #pragma unroll
            for (int kk = 0; kk < 32; kk += 2) {
                bf16x8 a0 = *(const bf16x8*)(hrd + kk * 64);
                bf16x8 a1 = *(const bf16x8*)(hrd + kk * 64 + 64);
                acc0 = __builtin_amdgcn_mfma_f32_16x16x32_bf16(a0, *(const bf16x8*)(wrd + kk * 2048),       acc0, 0, 0, 0);
                acc1 = __builtin_amdgcn_mfma_f32_16x16x32_bf16(a1, *(const bf16x8*)(wrd + (kk + 1) * 2048), acc1, 0, 0, 0);
            }

            // resolve xw (values are never bf16 0xFFFF; whole word 0xFFFFFFFF = poison)
            for (;;) {
                bool bad = false;
                #pragma unroll
                for (int r = 0; r < 4; ++r) bad |= (xww[r] == 0xFFFFFFFFu);
                if (!bad) break;
                #pragma unroll
                for (int r = 0; r < 4; ++r)
                    if (xww[r] == 0xFFFFFFFFu) {
                        const int bc = (kchunk * 4 + r) & 7;
                        const size_t row = (size_t)(t * 64 + group * 8 + bc);
                        xww[r] = __hip_atomic_load((const unsigned int*)(XWb + row * 1024 + jpair),
                                                   __ATOMIC_RELAXED, __HIP_MEMORY_SCOPE_AGENT);
                    }
            }

            bf16* rawN = raw + (size_t)(t + 1) * 65536;
            if (l < 32) {                            // rows 0-7 real
                #pragma unroll
                for (int r = 0; r < 4; ++r) {
                    const int b = (l >> 4) * 4 + r;
                    const unsigned short x16 = (jglob & 1) ? (unsigned short)(xww[r] >> 16)
                                                           : (unsigned short)(xww[r] & 0xFFFF);
                    const float xwv = __builtin_bit_cast(float, (unsigned int)x16 << 16);
                    const float V = acc0[r] + acc1[r] + bh;          // h @ Whh^T + b_hh
                    const float h = tanhf(xwv + V);                  // xw holds + b_ih
                    const size_t row = (size_t)(t * 64 + group * 8 + b);
                    Ust[row * 1024 + jglob] = (bf16)V;               // hiddens_U (no b_ih)
                    const bf16 hb = (bf16)h;
                    // inline pos: (h_t - h_{t+1} + eps)^2 at (b, jglob)
                    const float ht = (float)*(const bf16*)(Hlds + b * 2064 + jglob * 2);
                    const float pd = ht - (float)hb + EPSC;
                    posacc += pd * pd;
                    unsigned short hs = __builtin_bit_cast(unsigned short, hb);
                    unsigned short hn = (unsigned short)__shfl_down((int)hs, 1, 64);
                    if ((frow & 1) == 0) {                           // pack 2 cols -> 4B
                        unsigned int pack = (unsigned int)hs | ((unsigned int)hn << 16);
                        unsigned int* dst = (unsigned int*)(rawN + (size_t)(group * 8 + b) * 1024 + jglob);
                        __hip_atomic_store(dst, pack, __ATOMIC_RELAXED, __HIP_MEMORY_SCOPE_AGENT);
                    }
                }
            }
            if (t < 127) {
                __syncthreads();                     // store acks drained
                if (tid == 0)
                    __hip_atomic_fetch_add(&cnt[(((t + 1) * 8 + group) * 4 + (slot & 3)) * 32], 1,
                                           __ATOMIC_RELAXED, __HIP_MEMORY_SCOPE_AGENT);
            }
        }
        // pos partial: wave-reduce + one atomicAdd
        #pragma unroll
        for (int off2 = 32; off2 > 0; off2 >>= 1) posacc += __shfl_down(posacc, off2, 64);
        if (l == 0) atomicAdd(lacc, posacc * (TEMPC / 128.f));
    } else {
        // ================= GEMM roles: 128x128 tile, BK=32, dbuf, counted vmcnt ========
        bf16* As = (bf16*)pool;                      // 16KB (2 bufs)
        bf16* Bs = (bf16*)(pool + 16384);            // 16KB
        const int wr = w >> 1, wc = w & 1;
        const bool isXW = (id < 640);

        int mbase, nbase;
        const char *Asrc0, *Asrc1;
        const int r0 = w * 32 + (l >> 2);
        const int csw = ((l & 3) ^ ((l >> 3) & 3)) * 16;
        if (isXW) {
            const int q = id - 128;                  // mi-ascending: earliest rows first
            mbase = (q >> 3) * 128;
            nbase = (q & 7) * 128;
            Asrc0 = (const char*)emb + (size_t)data[mbase + r0] * 2048 + csw;
            Asrc1 = (const char*)emb + (size_t)data[mbase + r0 + 16] * 2048 + csw;
        } else {
            const int q  = id - 640;                 // 0..1999
            const int wg = (q & 7) * 250 + (q >> 3); // XCD swizzle
            mbase = (wg >> 3) * 128;
            nbase = (wg & 7) * 128;
            Asrc0 = (const char*)emb + (size_t)(mbase + r0) * 2048 + csw;
            Asrc1 = (const char*)emb + (size_t)(mbase + r0 + 16) * 2048 + csw;
        }
        const char* Bsrc0 = (const char*)Wih + (size_t)(nbase + r0) * 2048 + csw;
        const char* Bsrc1 = (const char*)Wih + (size_t)(nbase + r0 + 16) * 2048 + csw;

        const int frow  = l & 15;
        const int koffE = (((l >> 4) ^ ((frow >> 1) & 3)) * 8);
        const bf16* Ard = As + (wr * 64 + frow) * 32 + koffE;
        const bf16* Brd = Bs + (wc * 64 + frow) * 32 + koffE;

        auto stage = [&](int buf, int kb) {
            bf16* As_ = As + buf * 4096 + w * 1024;
            bf16* Bs_ = Bs + buf * 4096 + w * 1024;
            GLD_LDS16(Asrc0 + kb, As_);
            GLD_LDS16(Asrc1 + kb, As_ + 512);
            GLD_LDS16(Bsrc0 + kb, Bs_);
            GLD_LDS16(Bsrc1 + kb, Bs_ + 512);
        };

        stage(0, 0);
        stage(1, 64);

        f32x4 acc[4][4] = {};
        for (int k = 0; k < 32; ++k) {
            if (k == 31) asm volatile("s_waitcnt vmcnt(0)" ::: "memory");
            else         asm volatile("s_waitcnt vmcnt(4)" ::: "memory");
            __builtin_amdgcn_s_barrier();
            const bf16* Ab = Ard + (k & 1) * 4096;
            const bf16* Bb = Brd + (k & 1) * 4096;
            bf16x8 af[4], bfr[4];
            #pragma unroll
            for (int mt = 0; mt < 4; ++mt) af[mt]  = *(const bf16x8*)(Ab + mt * 16 * 32);
            #pragma unroll
            for (int nt = 0; nt < 4; ++nt) bfr[nt] = *(const bf16x8*)(Bb + nt * 16 * 32);
            #pragma unroll
            for (int mt = 0; mt < 4; ++mt)
                #pragma unroll
                for (int nt = 0; nt < 4; ++nt)
                    acc[mt][nt] = __builtin_amdgcn_mfma_f32_16x16x32_bf16(af[mt], bfr[nt], acc[mt][nt], 0, 0, 0);
            asm volatile("s_waitcnt lgkmcnt(0)" ::: "memory");
            __builtin_amdgcn_s_barrier();
            if (k + 2 < 32) stage(k & 1, (k + 2) * 64);
        }

        if (isXW) {
            // packed 4B agent-atomic stores (write-through -> RNN sees them; un-poisons)
            #pragma unroll
            for (int mt = 0; mt < 4; ++mt)
                #pragma unroll
                for (int nt = 0; nt < 4; ++nt) {
                    const int colg = nbase + wc * 64 + nt * 16 + frow;
                    const float bi = bih[colg];
                    #pragma unroll
                    for (int r = 0; r < 4; ++r) {
                        const int rowg = mbase + wr * 64 + mt * 16 + (l >> 4) * 4 + r;
                        const bf16 vb = (bf16)(acc[mt][nt][r] + bi);
                        unsigned short vs = __builtin_bit_cast(unsigned short, vb);
                        unsigned short vn = (unsigned short)__shfl_down((int)vs, 1, 64);
                        if ((frow & 1) == 0) {
                            unsigned int pack = (unsigned int)vs | ((unsigned int)vn << 16);
                            __hip_atomic_store((unsigned int*)(XWb + (size_t)rowg * 1024 + colg),
                                               pack, __ATOMIC_RELAXED, __HIP_MEMORY_SCOPE_AGENT);
                        }
                    }
                }
        } else {
            #pragma unroll
            for (int mt = 0; mt < 4; ++mt)
                #pragma unroll
                for (int nt = 0; nt < 4; ++nt) {
                    const int colg = nbase + wc * 64 + nt * 16 + frow;
                    const float bi = bih[colg];
                    #pragma unroll
                    for (int r = 0; r < 4; ++r) {
                        const int rowg = mbase + wr * 64 + mt * 16 + (l >> 4) * 4 + r;
                        P[(size_t)rowg * 1024 + colg] = (bf16)(acc[mt][nt][r] + bi);
                    }
                }
        }
    }
}

// ---------------- neg term: per row r, log(sum_s exp(-clip(||prev - tanh(P+U)||^2))) ---
__global__ __launch_bounds__(256)
void neg_kernel(const int* __restrict__ samples, const bf16* __restrict__ P,
                const bf16* __restrict__ Ust, const bf16* __restrict__ raw,
                float* __restrict__ lacc)
{
    const int l = threadIdx.x & 63;
    const int r = blockIdx.x * 4 + (threadIdx.x >> 6);   // row 0..8191
    const bf16* u  = Ust + (size_t)r * 1024;
    const bf16* pv = raw + (size_t)r * 1024;

    float uf[16], vf[16];
    {
        bf16x8 u0 = *(const bf16x8*)(u + l * 8);
        bf16x8 u1 = *(const bf16x8*)(u + 512 + l * 8);
        bf16x8 v0 = *(const bf16x8*)(pv + l * 8);
        bf16x8 v1 = *(const bf16x8*)(pv + 512 + l * 8);
        #pragma unroll
        for (int i = 0; i < 8; ++i) {
            uf[i] = (float)u0[i]; uf[8 + i] = (float)u1[i];
            vf[i] = (float)v0[i]; vf[8 + i] = (float)v1[i];
        }
    }

    float se = 0.f;
    #pragma unroll
    for (int s = 0; s < 10; ++s) {
        const int tok = samples[s * 8192 + r];
        const bf16* pr = P + (size_t)tok * 1024;
        bf16x8 p0 = *(const bf16x8*)(pr + l * 8);
        bf16x8 p1 = *(const bf16x8*)(pr + 512 + l * 8);
        float d2 = 0.f;
        #pragma unroll
        for (int i = 0; i < 8; ++i) {
            const float o0 = tanhf((float)p0[i] + uf[i]);
            const float d0 = vf[i] - o0 + EPSC;
            d2 += d0 * d0;
            const float o1 = tanhf((float)p1[i] + uf[8 + i]);
            const float d1 = vf[8 + i] - o1 + EPSC;
            d2 += d1 * d1;
        }
        #pragma unroll
        for (int off = 1; off < 64; off <<= 1)
            d2 += __shfl_xor(d2, off, 64);
        se += expf(-fminf(d2, 0.01f));               // d2 >= 0 already
    }
    if (l == 0) atomicAdd(lacc, logf(se * (1.f / 8192.f) + EPSC));
}

// ---------------- finalize ----------------
__global__ void fin_kernel(const float* __restrict__ lacc, float* __restrict__ out)
{
    if (threadIdx.x == 0) out[0] = lacc[0];
}

extern "C" void kernel_launch(void* const* d_in, const int* in_sizes, int n_in,
                              void* d_out, int out_size, void* d_ws, size_t ws_size,
                              hipStream_t stream)
{
    const int*   data    = (const int*)d_in[0];   // [128*64]
    const int*   samples = (const int*)d_in[1];   // [10*8192]
    const float* emb     = (const float*)d_in[2]; // [32000*1024]
    const float* Wih     = (const float*)d_in[3]; // [1024*1024]
    const float* bih     = (const float*)d_in[4]; // [1024]
    const float* Whh     = (const float*)d_in[5]; // [1024*1024]
    const float* bhh     = (const float*)d_in[6]; // [1024]

    char* ws = (char*)d_ws;
    size_t off = 0;
    auto alloc = [&](size_t bytes) { void* p = ws + off; off += (bytes + 255) & ~(size_t)255; return p; };
    bf16*  emb_b = (bf16*)alloc((size_t)32000 * 1024 * 2);
    bf16*  Wih_b = (bf16*)alloc((size_t)1024 * 1024 * 2);
    bf16*  Whh_b = (bf16*)alloc((size_t)1024 * 1024 * 2);
    bf16*  P     = (bf16*)alloc((size_t)32000 * 1024 * 2);
    bf16*  XWb   = (bf16*)alloc((size_t)8192 * 1024 * 2);
    bf16*  Ust   = (bf16*)alloc((size_t)8192 * 1024 * 2);
    bf16*  raw   = (bf16*)alloc((size_t)129 * 64 * 1024 * 2);
    float* lacc  = (float*)alloc(256);
    int*   cnt   = (int*)alloc(524288);

    hipMemsetAsync(raw, 0, 64 * 1024 * 2, stream);                    // h0 = 0
    hipMemsetAsync(XWb, 0xFF, (size_t)8192 * 1024 * 2, stream);       // poison XWb
    hipMemsetAsync(lacc, 0, 256, stream);
    hipMemsetAsync(cnt,  0, 524288, stream);                          // step counters

    // all three f32->bf16 conversions in one launch
    conv3_kernel<<<2048, 256, 0, stream>>>(emb, emb_b, Wih, Wih_b, Whh, Whh_b);

    // FUSED: 128 RNN blocks + 512 XWb tiles (priority) + 2000 P tiles
    fused_kernel<<<2640, 256, 0, stream>>>(data, emb_b, Wih_b, bih, P,
                                           raw, Whh_b, XWb, bhh, Ust, cnt, lacc);

    // neg term: gather-elementwise over samples (no GEMM)
    neg_kernel<<<2048, 256, 0, stream>>>(samples, P, Ust, raw, lacc);

    fin_kernel<<<1, 64, 0, stream>>>(lacc, (float*)d_out);
}